// Round 5
// baseline (87.888 us; speedup 1.0000x reference)
//
#include <hip/hip_runtime.h>

// out[b,c,y,x] = sum_{dy,dx} f[b,c,y+dy-3,x+dx-3] * ker[b,dy,dx,y,x]
// MFMA per 16-px strip: D[m=c][n=px] += A[m][k] * B[k][n];
//   window origin gx0-4:  A[m][k] = fbf[c0+m, y+dy-3, gx0-4+nt*16+k]
//   B[k][n] = bf16(ker[dy, k-n-1, y, gx0+nt*16+n]) for k-n-1 in [0,6], else 0
// Band k in [n+1, n+7] <= 22 < 24, so kb=3 lanes supply zero B fragments.

#define BATCH 4
#define CHAN 96
#define HW_ 256
#define HWPIX 65536
#define KS 7
#define XT 64
#define YT 16
#define NTHR 512
#define XPITCH 72                    // shorts per (row,c); 144 B, 16B-aligned
#define ROWSTRIDE (CHAN * XPITCH)    // 6912 shorts
#define RING_S (8 * ROWSTRIDE)       // 55296 shorts = 110592 B
#define NPAIR 36                     // XWIN=72 px staged as 36 aligned pairs
#define FSLOTS (CHAN * NPAIR)        // 3456
#define FSPT 7
#define BT_K 24                      // stored k-dim (band max 22, pad to 24)
#define BT_NROW (KS * BT_K)          // 168 shorts per n
#define BT_STRIP (16 * BT_NROW + 8)  // 2696 shorts (+8 pad: breaks 4-way write conflict)
#define BT_BUF (4 * BT_STRIP)        // 10784 shorts per buffer
#define BT_DW (BT_BUF)               // dwords to zero = 2*BT_BUF/2
#define KVALS (KS * KS * XT)         // 3136
#define KSPT 7
#define LDS_BYTES ((RING_S + 2 * BT_BUF) * 2)   // 153728 B

typedef __attribute__((ext_vector_type(8))) short short8v;
typedef __attribute__((ext_vector_type(4))) float f32x4;

static __device__ __forceinline__ unsigned short f2bf(float x) {
    union { float f; unsigned u; } v; v.f = x;
    unsigned u = v.u + 0x7fffu + ((v.u >> 16) & 1u);
    return (unsigned short)(u >> 16);
}

// barrier that drains LDS ops only; global loads/stores stay in flight (T4)
#define LDS_BARRIER() asm volatile("s_waitcnt lgkmcnt(0)\ns_barrier" ::: "memory")

__global__ __launch_bounds__(NTHR)
void svconv_mfma3(const float* __restrict__ K_, const float* __restrict__ F_,
                  float* __restrict__ O_) {
    extern __shared__ short lds[];
    unsigned* lds32 = (unsigned*)lds;
    short* BT = lds + RING_S;

    const int tid = threadIdx.x;
    const int xt = blockIdx.x, yt = blockIdx.y, b = blockIdx.z;
    const int gx0 = xt * XT, gy0 = yt * YT;
    const int wave = tid >> 6, lane = tid & 63;
    const int nt = wave & 3, ch = wave >> 2;   // n-strip 0..3, c-half 0..1
    const int n = lane & 15, kb = lane >> 4;   // frag col / k-group

    // ---- zero both BT buffers once: non-band slots must stay 0 forever
    {
        unsigned* bt32 = (unsigned*)BT;        // BT_DW dwords
#pragma unroll
        for (int i = 0; i < 22; ++i) {
            int idx = tid + NTHR * i;
            if (idx < BT_DW) bt32[idx] = 0u;
        }
    }

    // ---- feature staging slots (iteration-invariant); window origin gx0-4,
    // pairs 8B-aligned and never straddle the image edge -> single mask
    int fldsoff[FSPT], fgof[FSPT];
    bool fin[FSPT];
#pragma unroll
    for (int i = 0; i < FSPT; ++i) {
        int idx = tid + NTHR * i;
        if (idx < FSLOTS) {
            int c = idx / NPAIR;
            int xi0 = 2 * (idx - c * NPAIR);
            int x0e = gx0 - 4 + xi0;
            fldsoff[i] = c * XPITCH + xi0;
            fgof[i] = c * HWPIX + x0e;
            fin[i] = ((unsigned)x0e < (unsigned)HW_);
        } else { fldsoff[i] = -1; fgof[i] = 0; fin[i] = false; }
    }

    // ---- K staging slots: coalesced source, scattered 2B band writes
    // BT[nt][n][dy][n+dx+1]
    int kgoff[KSPT], kldsoff[KSPT];
#pragma unroll
    for (int i = 0; i < KSPT; ++i) {
        int idx = tid + NTHR * i;
        if (idx < KVALS) {
            int dydx = idx >> 6, xl = idx & 63;
            int dy = dydx / KS, dx = dydx - KS * dy;
            int sn = xl & 15, snt = xl >> 4;
            kgoff[i] = dydx * HWPIX + gx0 + xl;
            kldsoff[i] = snt * BT_STRIP + sn * BT_NROW + dy * BT_K + (sn + dx + 1);
        } else { kgoff[i] = 0; kldsoff[i] = -1; }
    }

    const float* Fb = F_ + (size_t)b * CHAN * HWPIX;
    const float* Kb = K_ + (size_t)b * KS * KS * HWPIX;

    __syncthreads();   // BT zeros visible before band writes

    // ---- prologue: ring rows gy0-3..gy0+3 (OOB -> 0)
    for (int r = -3; r <= 3; ++r) {
        int yr = gy0 + r;
        bool yok = ((unsigned)yr < (unsigned)HW_);
        int rbase = (yr & 7) * ROWSTRIDE;
#pragma unroll
        for (int i = 0; i < FSPT; ++i) {
            if (fldsoff[i] >= 0) {
                float f0 = 0.f, f1 = 0.f;
                if (yok && fin[i]) {
                    float2 v = *(const float2*)(Fb + (size_t)yr * HW_ + fgof[i]);
                    f0 = v.x; f1 = v.y;
                }
                lds32[(rbase + fldsoff[i]) >> 1] =
                    (unsigned)f2bf(f0) | ((unsigned)f2bf(f1) << 16);
            }
        }
    }
    // ---- prologue: K row gy0 -> BT buf 0
#pragma unroll
    for (int i = 0; i < KSPT; ++i)
        if (kldsoff[i] >= 0)
            BT[kldsoff[i]] = (short)f2bf(Kb[kgoff[i] + gy0 * HW_]);

    // ---- register prefetch: ring row gy0+4 (in-image), K row gy0+1
    float rr0[FSPT], rr1[FSPT], krf[KSPT];
    {
        const int yr = gy0 + 4;
#pragma unroll
        for (int i = 0; i < FSPT; ++i) {
            rr0[i] = 0.f; rr1[i] = 0.f;
            if (fin[i]) {
                float2 v = *(const float2*)(Fb + (size_t)yr * HW_ + fgof[i]);
                rr0[i] = v.x; rr1[i] = v.y;
            }
        }
#pragma unroll
        for (int i = 0; i < KSPT; ++i)
            krf[i] = (kldsoff[i] >= 0) ? Kb[kgoff[i] + (gy0 + 1) * HW_] : 0.f;
    }

    const int kcl8 = (kb == 3) ? 0 : kb * 8;   // kb=3: B=0, A read aliases kb=0 (broadcast)
    const int aoffc = (ch * 48 + n) * XPITCH + nt * 16 + kcl8;
    float* ob = O_ + ((size_t)(b * CHAN + ch * 48 + kb * 4)) * HWPIX
              + gx0 + nt * 16 + n;
    const short8v bzero = {0, 0, 0, 0, 0, 0, 0, 0};

#pragma unroll 1
    for (int t = 0; t < YT; ++t) {
        const int y = gy0 + t;
        // LDS-only barrier: prev-iter LDS writes visible, prev reads drained;
        // global prefetch loads issued last iter STAY IN FLIGHT across it.
        LDS_BARRIER();

        // B fragments: 7x ds_read_b128 from BT[t&1]
        const short* btp = BT + (t & 1) * BT_BUF + nt * BT_STRIP + n * BT_NROW + kb * 8;
        short8v bfr[KS];
#pragma unroll
        for (int dy = 0; dy < KS; ++dy)
            bfr[dy] = (kb < 3) ? *(const short8v*)(btp + dy * BT_K) : bzero;

        // A reads + MFMA (3 c-tiles, dy-chained accumulators)
        f32x4 acc0 = {0,0,0,0}, acc1 = {0,0,0,0}, acc2 = {0,0,0,0};
        __builtin_amdgcn_s_setprio(1);
#pragma unroll
        for (int dy = 0; dy < KS; ++dy) {
            const short* ap = lds + ((y + dy - 3) & 7) * ROWSTRIDE + aoffc;
            acc0 = __builtin_amdgcn_mfma_f32_16x16x32_bf16(*(const short8v*)(ap), bfr[dy], acc0, 0, 0, 0);
            acc1 = __builtin_amdgcn_mfma_f32_16x16x32_bf16(*(const short8v*)(ap + 16 * XPITCH), bfr[dy], acc1, 0, 0, 0);
            acc2 = __builtin_amdgcn_mfma_f32_16x16x32_bf16(*(const short8v*)(ap + 32 * XPITCH), bfr[dy], acc2, 0, 0, 0);
        }
        __builtin_amdgcn_s_setprio(0);

        // stores: D col = lane&15 (px), row = kb*4+r (channel)
        {
            float* op = ob + (size_t)y * HW_;
#pragma unroll
            for (int r = 0; r < 4; ++r) {
                op[(size_t)r * HWPIX]        = acc0[r];
                op[(size_t)(16 + r) * HWPIX] = acc1[r];
                op[(size_t)(32 + r) * HWPIX] = acc2[r];
            }
        }

        if (t < YT - 1) {
            // ring row y+4 (slot disjoint from all rows read this phase);
            // vmcnt wait for rr/krf lands here, one full iteration after issue
            int rbase = ((y + 4) & 7) * ROWSTRIDE;
#pragma unroll
            for (int i = 0; i < FSPT; ++i)
                if (fldsoff[i] >= 0)
                    lds32[(rbase + fldsoff[i]) >> 1] =
                        (unsigned)f2bf(rr0[i]) | ((unsigned)f2bf(rr1[i]) << 16);
            // BT[(t+1)&1] for row y+1 (opposite buffer from this phase's reads)
            short* btw = BT + ((t + 1) & 1) * BT_BUF;
#pragma unroll
            for (int i = 0; i < KSPT; ++i)
                if (kldsoff[i] >= 0) btw[kldsoff[i]] = (short)f2bf(krf[i]);
        }

        // issue next prefetches; they fly across the next barrier (T14/T4)
        if (t < YT - 2) {
            int yr = y + 5;
            bool yok = ((unsigned)yr < (unsigned)HW_);
#pragma unroll
            for (int i = 0; i < FSPT; ++i) {
                rr0[i] = 0.f; rr1[i] = 0.f;
                if (yok && fin[i]) {
                    float2 v = *(const float2*)(Fb + (size_t)yr * HW_ + fgof[i]);
                    rr0[i] = v.x; rr1[i] = v.y;
                }
            }
            const int yk = y + 2;   // t <= YT-3 -> yk <= gy0+15 <= 255
#pragma unroll
            for (int i = 0; i < KSPT; ++i)
                if (kldsoff[i] >= 0) krf[i] = Kb[kgoff[i] + yk * HW_];
        }
    }
}

extern "C" void kernel_launch(void* const* d_in, const int* in_sizes, int n_in,
                              void* d_out, int out_size, void* d_ws, size_t ws_size,
                              hipStream_t stream) {
    const float* kernels  = (const float*)d_in[0];  // [4,7,7,256,256]
    const float* features = (const float*)d_in[1];  // [4,96,256,256]
    float* out = (float*)d_out;                     // [4,96,256,256]

    hipFuncSetAttribute(reinterpret_cast<const void*>(&svconv_mfma3),
                        hipFuncAttributeMaxDynamicSharedMemorySize, LDS_BYTES);

    dim3 grid(HW_ / XT, HW_ / YT, BATCH);  // (4, 16, 4) = 256 blocks = 1/CU
    dim3 block(NTHR);
    svconv_mfma3<<<grid, block, LDS_BYTES, stream>>>(kernels, features, out);
}

// Round 6
// 83.910 us; speedup vs baseline: 1.0474x; 1.0474x over previous
//
#include <hip/hip_runtime.h>
#include <hip/hip_bf16.h>

// out[b,c,y,x] = sum_{dy,dx} f[b,c,y+dy-3,x+dx-3] * ker[b,dy,dx,y,x]
// MFMA per 16-px strip: D[m=c][n=px] += A[m][k] * B[k][n];
//   A[m][k] = bf16(feat[c0+m, y+dy-3, gx0-4+nt*16+k])  -- held in a VGPR ring
//   B[k][n] = bf16(ker[dy, k-n-1, y, gx0+nt*16+n]) for k-n-1 in [0,6], else 0
// A-ring: 8 rows x 3 c-tiles in VGPRs, statically indexed (full unroll).
// Only B goes through LDS (double-buffered BT, band layout).

#define BATCH 4
#define CHAN 96
#define HW_ 256
#define HWPIX 65536
#define KS 7
#define XT 64
#define YT 16
#define NTHR 512
#define BT_K 24                      // stored k-dim (band max 22, pad to 24)
#define BT_NROW (KS * BT_K)          // 168 shorts per n
#define BT_STRIP (16 * BT_NROW + 8)  // 2696 shorts
#define BT_BUF (4 * BT_STRIP)        // 10784 shorts per buffer
#define KVALS (KS * KS * XT)         // 3136
#define KSPT 7
#define FTOT ((size_t)BATCH * CHAN * HWPIX)

typedef __attribute__((ext_vector_type(8))) short short8v;
typedef __attribute__((ext_vector_type(4))) float f32x4;

union S8 { short8v s; unsigned u[4]; };

static __device__ __forceinline__ unsigned pkbf(float a, float b) {
    union { __hip_bfloat162 h; unsigned u; } c;
    c.h = __float22bfloat162_rn(make_float2(a, b));
    return c.u;
}
static __device__ __forceinline__ short bfbits(float x) {
    union { __hip_bfloat16 h; short s; } c;
    c.h = __float2bfloat16(x);
    return c.s;
}

struct AF { float4 v[3][2]; };

__global__ __launch_bounds__(NTHR)
void svconv_mfma4(const float* __restrict__ K_, const float* __restrict__ F_,
                  float* __restrict__ O_) {
    __shared__ short BT[2 * BT_BUF];   // 43136 B

    const int tid = threadIdx.x;
    const int xt = blockIdx.x, yt = blockIdx.y, b = blockIdx.z;
    const int gx0 = xt * XT, gy0 = yt * YT;
    const int wave = tid >> 6, lane = tid & 63;
    const int nt = wave & 3, ch = wave >> 2;   // n-strip 0..3, c-half 0..1
    const int n = lane & 15, kb = lane >> 4;   // frag col / k-group

    // ---- A-operand addressing (y-invariant): lane supplies A[m=n][k=kb*8+j]
    const int xs = gx0 - 4 + nt * 16 + kb * 8;   // xs % 4 == 0
    const float* lo = F_;
    const float* hiq = F_ + FTOT - 4;            // clamp bound per float4
    const float* abase[3];
#pragma unroll
    for (int ct = 0; ct < 3; ++ct)
        abase[ct] = F_ + ((size_t)(b * CHAN + ch * 48 + ct * 16 + n)) * HWPIX + xs;

    // x-validity mask, packed per bf16 element (each float4 quad homogeneous)
    unsigned xm[4];
#pragma unroll
    for (int i = 0; i < 4; ++i) {
        unsigned m0 = ((unsigned)(xs + 2 * i) < (unsigned)HW_) ? 0xFFFFu : 0u;
        unsigned m1 = ((unsigned)(xs + 2 * i + 1) < (unsigned)HW_) ? 0xFFFFu : 0u;
        xm[i] = m0 | (m1 << 16);
    }

    short8v ar[8][3];   // A ring: 8 rows x 3 c-tiles (static indexing only)

    auto issueA = [&](int yr, AF& f) {
#pragma unroll
        for (int ct = 0; ct < 3; ++ct) {
            const float* p = abase[ct] + (size_t)yr * HW_;
            const float* p0 = p;
            const float* p1 = p + 4;
            p0 = p0 < lo ? lo : (p0 > hiq ? hiq : p0);
            p1 = p1 < lo ? lo : (p1 > hiq ? hiq : p1);
            f.v[ct][0] = *(const float4*)p0;
            f.v[ct][1] = *(const float4*)p1;
        }
    };
    auto commitA = [&](int slot, const AF& f, bool yok) {
#pragma unroll
        for (int ct = 0; ct < 3; ++ct) {
            S8 v;
            if (yok) {
                v.u[0] = pkbf(f.v[ct][0].x, f.v[ct][0].y) & xm[0];
                v.u[1] = pkbf(f.v[ct][0].z, f.v[ct][0].w) & xm[1];
                v.u[2] = pkbf(f.v[ct][1].x, f.v[ct][1].y) & xm[2];
                v.u[3] = pkbf(f.v[ct][1].z, f.v[ct][1].w) & xm[3];
            } else {
                v.u[0] = 0; v.u[1] = 0; v.u[2] = 0; v.u[3] = 0;
            }
            ar[slot][ct] = v.s;
        }
    };

    // ---- K band staging slots: coalesced source, scattered 2B band writes
    int kgoff[KSPT], kldsoff[KSPT];
#pragma unroll
    for (int i = 0; i < KSPT; ++i) {
        int idx = tid + NTHR * i;
        if (idx < KVALS) {
            int dydx = idx >> 6, xl = idx & 63;
            int dy = dydx / KS, dx = dydx - KS * dy;
            int sn = xl & 15, snt = xl >> 4;
            kgoff[i] = dydx * HWPIX + gx0 + xl;
            kldsoff[i] = snt * BT_STRIP + sn * BT_NROW + dy * BT_K + (sn + dx + 1);
        } else { kgoff[i] = 0; kldsoff[i] = -1; }
    }
    const float* Kb = K_ + (size_t)b * KS * KS * HWPIX;

    // ---- zero both BT buffers (non-band slots must stay 0 forever)
    {
        unsigned* bt32 = (unsigned*)BT;   // BT_BUF dwords total
#pragma unroll
        for (int i = 0; i < 22; ++i) {
            int idx = tid + NTHR * i;
            if (idx < BT_BUF) bt32[idx] = 0u;
        }
    }

    // ---- K prologue loads (row gy0) into registers; land under A prologue
    float kr0[KSPT];
#pragma unroll
    for (int i = 0; i < KSPT; ++i)
        kr0[i] = (kldsoff[i] >= 0) ? Kb[kgoff[i] + (size_t)gy0 * HW_] : 0.f;

    __syncthreads();   // BT zeros visible before band writes

    // ---- A prologue: rows gy0-3..gy0+3 -> ring slots (2-deep issue/commit)
    AF afa, afb;
    issueA(gy0 - 3, afa);
#pragma unroll
    for (int r = 0; r < 7; ++r) {
        AF& cur = (r & 1) ? afb : afa;
        AF& nxt = (r & 1) ? afa : afb;
        if (r < 6) issueA(gy0 + r - 2, nxt);
        const int yr = gy0 + r - 3;
        commitA((r + 5) & 7, cur, (unsigned)yr < (unsigned)HW_);
    }

    // ---- band-write prologue K -> buf0 (visible after loop-top barrier)
#pragma unroll
    for (int i = 0; i < KSPT; ++i)
        if (kldsoff[i] >= 0) BT[kldsoff[i]] = bfbits(kr0[i]);

    const short8v bzero = {0, 0, 0, 0, 0, 0, 0, 0};
    float* ob = O_ + ((size_t)(b * CHAN + ch * 48 + kb * 4)) * HWPIX
              + gx0 + nt * 16 + n;
    float krf[KSPT];
    AF af;

#pragma unroll
    for (int t = 0; t < YT; ++t) {
        const int y = gy0 + t;
        __syncthreads();   // buf[t&1] band writes visible; buf[(t+1)&1] free

        // issue next K row loads EARLY (consumed at end of this iteration)
        if (t < YT - 1) {
#pragma unroll
            for (int i = 0; i < KSPT; ++i)
                krf[i] = (kldsoff[i] >= 0)
                       ? Kb[kgoff[i] + (size_t)(y + 1) * HW_] : 0.f;
        }
        // issue next A row loads EARLY (committed at end of this iteration)
        const bool pyok = (y + 4 < HW_);
        if (pyok) issueA(y + 4, af);

        // B fragments: 7x ds_read_b128 from BT[t&1]
        const short* btp = BT + (t & 1) * BT_BUF + nt * BT_STRIP + n * BT_NROW + kb * 8;
        short8v bfr[KS];
#pragma unroll
        for (int dy = 0; dy < KS; ++dy)
            bfr[dy] = (kb < 3) ? *(const short8v*)(btp + dy * BT_K) : bzero;

        // MFMA: 3 c-tiles x 7 dy, A from VGPR ring (static slots)
        f32x4 acc0 = {0,0,0,0}, acc1 = {0,0,0,0}, acc2 = {0,0,0,0};
#pragma unroll
        for (int dy = 0; dy < KS; ++dy) {
            const int sl = (t + dy + 5) & 7;   // (y+dy-3)&7, compile-time
            acc0 = __builtin_amdgcn_mfma_f32_16x16x32_bf16(ar[sl][0], bfr[dy], acc0, 0, 0, 0);
            acc1 = __builtin_amdgcn_mfma_f32_16x16x32_bf16(ar[sl][1], bfr[dy], acc1, 0, 0, 0);
            acc2 = __builtin_amdgcn_mfma_f32_16x16x32_bf16(ar[sl][2], bfr[dy], acc2, 0, 0, 0);
        }

        // stores: D col = lane&15 (px), row = kb*4+r (channel)
        {
            float* op = ob + (size_t)y * HW_;
#pragma unroll
            for (int r = 0; r < 4; ++r) {
                op[(size_t)r * HWPIX]        = acc0[r];
                op[(size_t)(16 + r) * HWPIX] = acc1[r];
                op[(size_t)(32 + r) * HWPIX] = acc2[r];
            }
        }

        // commit A row y+4 into ring slot (t+4)&7 (disjoint from slots read)
        commitA((t + 4) & 7, af, pyok);

        // band-write K row y+1 into the opposite BT buffer
        if (t < YT - 1) {
            short* btw = BT + ((t + 1) & 1) * BT_BUF;
#pragma unroll
            for (int i = 0; i < KSPT; ++i)
                if (kldsoff[i] >= 0) btw[kldsoff[i]] = bfbits(krf[i]);
        }
    }
}

extern "C" void kernel_launch(void* const* d_in, const int* in_sizes, int n_in,
                              void* d_out, int out_size, void* d_ws, size_t ws_size,
                              hipStream_t stream) {
    const float* kernels  = (const float*)d_in[0];  // [4,7,7,256,256]
    const float* features = (const float*)d_in[1];  // [4,96,256,256]
    float* out = (float*)d_out;                     // [4,96,256,256]

    dim3 grid(HW_ / XT, HW_ / YT, BATCH);  // (4, 16, 4) = 256 blocks = 1/CU
    dim3 block(NTHR);
    svconv_mfma4<<<grid, block, 0, stream>>>(kernels, features, out);
}